// Round 5
// baseline (3903.281 us; speedup 1.0000x reference)
//
#include <hip/hip_runtime.h>
#include <math.h>

#define N_CODES 4096
#define N_EDGES 8192
#define EMB     128
#define NHEAD   4
#define NNZ     65536
#define K_TOP   6553            // int(0.1 * 65536)
#define S_TOTAL 33554432        // 4096 * 8192
#define NBINS   8192            // 32 KB LDS histogram
#define CAP2    131072          // wide candidate cap
#define SLACK_BINS 160          // 0.039 of screening slack below the k-th bin

// ---------------- threefry2x32, JAX partitionable scheme, 32-bit path ----------------
// bits[idx] = w0 ^ w1 of threefry2x32(key=(0,42), ctr=(hi32(idx), lo32(idx)))
__device__ __forceinline__ unsigned rotl32(unsigned v, int r) {
  return (v << r) | (v >> (32 - r));
}

__device__ float jax_u42(unsigned pos) {
  const unsigned ks0 = 0u, ks1 = 42u, ks2 = 0x1BD11BDAu ^ 0u ^ 42u;
  unsigned x0 = 0u  + ks0;   // counts_hi + ks0
  unsigned x1 = pos + ks1;   // counts_lo + ks1
#define TFR(r) { x0 += x1; x1 = rotl32(x1, (r)); x1 ^= x0; }
  TFR(13) TFR(15) TFR(26) TFR(6)   x0 += ks1; x1 += ks2 + 1u;
  TFR(17) TFR(29) TFR(16) TFR(24)  x0 += ks2; x1 += ks0 + 2u;
  TFR(13) TFR(15) TFR(26) TFR(6)   x0 += ks0; x1 += ks1 + 3u;
  TFR(17) TFR(29) TFR(16) TFR(24)  x0 += ks1; x1 += ks2 + 4u;
  TFR(13) TFR(15) TFR(26) TFR(6)   x0 += ks2; x1 += ks0 + 5u;
#undef TFR
  unsigned bits = x0 ^ x1;   // 32-bit partitionable path XORs the two output words
  unsigned fb = (bits >> 9) | 0x3f800000u;
  float f = __uint_as_float(fb) - 1.0f;
  const float minv = 1e-6f;
  const float maxv = (float)(1.0 - 1e-6);
  float u = f * (maxv - minv) + minv;
  return fmaxf(minv, u);
}

__device__ float mask_val(float p, unsigned pos) {
  float u = jax_u42(pos);
  float l = (logf(p) - log1pf(-p) + logf(u) - log1pf(-u)) * 2.0f; // /TEMP, TEMP=0.5
  return 1.0f / (1.0f + expf(-l));
}

// ---------------- K1: per-edge counts ----------------
__global__ void count_k(const int* __restrict__ E, int* __restrict__ cnt) {
  int i = blockIdx.x * blockDim.x + threadIdx.x;
  if (i < NNZ) atomicAdd(&cnt[E[i]], 1);
}

// ---------------- K2: exclusive scan of 8192 counts ----------------
__global__ __launch_bounds__(1024) void scan_k(const int* __restrict__ cnt,
                                               int* __restrict__ offs) {
  __shared__ int part[1024];
  int t = threadIdx.x;
  int local[8]; int s = 0;
  for (int j = 0; j < 8; ++j) { local[j] = cnt[t * 8 + j]; s += local[j]; }
  part[t] = s; __syncthreads();
  int v = s;
  for (int o = 1; o < 1024; o <<= 1) {
    int add = (t >= o) ? part[t - o] : 0;
    __syncthreads();
    v += add; part[t] = v;
    __syncthreads();
  }
  int base = v - s;
  for (int j = 0; j < 8; ++j) { offs[t * 8 + j] = base; base += local[j]; }
}

// ---------------- K3: bucket scatter (CSR) ----------------
__global__ void scatter_k(const int* __restrict__ E, const int* __restrict__ offs,
                          int* __restrict__ cursor, int* __restrict__ bucket) {
  int i = blockIdx.x * blockDim.x + threadIdx.x;
  if (i < NNZ) {
    int e = E[i];
    int p = atomicAdd(&cursor[e], 1);
    bucket[offs[e] + p] = i;
  }
}

// ---------------- K4: sort CSR lists, edge means eX (f32) + recip norms; write sorted back ----------------
__global__ __launch_bounds__(128) void edge_k(const float* __restrict__ X,
                                              const int* __restrict__ V,
                                              const int* __restrict__ cnt,
                                              const int* __restrict__ offs,
                                              int* __restrict__ bucket,
                                              const float* __restrict__ W,
                                              float* __restrict__ eX,
                                              float* __restrict__ ne) {
  __shared__ int lst[512];
  __shared__ float red[2];
  int m = blockIdx.x, t = threadIdx.x;
  int deg = cnt[m], off = offs[m];
  int n = min(deg, 512);
  for (int j = t; j < n; j += 128) lst[j] = bucket[off + j];
  __syncthreads();
  if (t == 0 && n > 1) {             // ascending-index order == np.add.at order
    for (int a = 1; a < n; ++a) {
      int key = lst[a]; int b = a - 1;
      while (b >= 0 && lst[b] > key) { lst[b + 1] = lst[b]; --b; }
      lst[b + 1] = key;
    }
  }
  __syncthreads();
  for (int j = t; j < n; j += 128) bucket[off + j] = lst[j];  // sorted CSR for rescore
  float s = 0.f;
  for (int j = 0; j < n; ++j) s += X[(size_t)V[lst[j]] * EMB + t];
  float eXd = s / fmaxf((float)deg, 1.0f);
  eX[(size_t)m * EMB + t] = eXd;
  int lane = t & 63, wv = t >> 6;
  for (int h = 0; h < NHEAD; ++h) {
    float val = eXd * W[h * EMB + t];
    float ss = val * val;
    for (int o = 32; o > 0; o >>= 1) ss += __shfl_down(ss, o, 64);
    if (lane == 0) red[wv] = ss;
    __syncthreads();
    if (t == 0) ne[m * NHEAD + h] = 1.0f / fmaxf(sqrtf(red[0] + red[1]), 1e-6f);
    __syncthreads();
  }
}

// ---------------- K5: node recip head-norms ----------------
__global__ __launch_bounds__(128) void node_k(const float* __restrict__ X,
                                              const float* __restrict__ W,
                                              float* __restrict__ nn) {
  __shared__ float red[2];
  int n = blockIdx.x, t = threadIdx.x;
  float xd = X[(size_t)n * EMB + t];
  int lane = t & 63, wv = t >> 6;
  for (int h = 0; h < NHEAD; ++h) {
    float val = xd * W[h * EMB + t];
    float ss = val * val;
    for (int o = 32; o > 0; o >>= 1) ss += __shfl_down(ss, o, 64);
    if (lane == 0) red[wv] = ss;
    __syncthreads();
    if (t == 0) nn[n * NHEAD + h] = 1.0f / fmaxf(sqrtf(red[0] + red[1]), 1e-6f);
    __syncthreads();
  }
}

// ---------------- K6: fused-normalization fp32 GEMM (screening only) ----------------
__global__ __launch_bounds__(256) void gemm_fused(const float* __restrict__ X,
                                                  const float* __restrict__ eX,
                                                  const float* __restrict__ W,
                                                  const float* __restrict__ nn,
                                                  const float* __restrict__ ne,
                                                  float* __restrict__ C) {
  __shared__ float As[16][132];
  __shared__ float Bs[16][132];
  const int tid  = threadIdx.x;
  const int n0   = blockIdx.y * 128;
  const int m0   = blockIdx.x * 128;
  const int tn   = tid & 15;
  const int tm   = tid >> 4;
  const int lrow = tid >> 2;
  const int lc   = (tid & 3) << 2;

  float acc[8][8];
#pragma unroll
  for (int i = 0; i < 8; ++i)
#pragma unroll
    for (int j = 0; j < 8; ++j) acc[i][j] = 0.f;

  for (int k0 = 0; k0 < 512; k0 += 16) {
    const int h  = k0 >> 7;
    const int d0 = (k0 & 127) + lc;
    float4 a0 = *(const float4*)(X  + (size_t)(n0 + lrow)      * EMB + d0);
    float4 a1 = *(const float4*)(X  + (size_t)(n0 + lrow + 64) * EMB + d0);
    float4 b0 = *(const float4*)(eX + (size_t)(m0 + lrow)      * EMB + d0);
    float4 b1 = *(const float4*)(eX + (size_t)(m0 + lrow + 64) * EMB + d0);
    float rna0 = nn[(n0 + lrow)      * NHEAD + h];
    float rna1 = nn[(n0 + lrow + 64) * NHEAD + h];
    float reb0 = ne[(m0 + lrow)      * NHEAD + h];
    float reb1 = ne[(m0 + lrow + 64) * NHEAD + h];
    float wsq[4];
#pragma unroll
    for (int c = 0; c < 4; ++c) {
      float wv = W[h * EMB + d0 + c];
      wsq[c] = wv * wv;
    }
    __syncthreads();
    As[lc + 0][lrow] = a0.x * rna0; As[lc + 1][lrow] = a0.y * rna0;
    As[lc + 2][lrow] = a0.z * rna0; As[lc + 3][lrow] = a0.w * rna0;
    As[lc + 0][lrow + 64] = a1.x * rna1; As[lc + 1][lrow + 64] = a1.y * rna1;
    As[lc + 2][lrow + 64] = a1.z * rna1; As[lc + 3][lrow + 64] = a1.w * rna1;
    Bs[lc + 0][lrow] = b0.x * wsq[0] * reb0; Bs[lc + 1][lrow] = b0.y * wsq[1] * reb0;
    Bs[lc + 2][lrow] = b0.z * wsq[2] * reb0; Bs[lc + 3][lrow] = b0.w * wsq[3] * reb0;
    Bs[lc + 0][lrow + 64] = b1.x * wsq[0] * reb1; Bs[lc + 1][lrow + 64] = b1.y * wsq[1] * reb1;
    Bs[lc + 2][lrow + 64] = b1.z * wsq[2] * reb1; Bs[lc + 3][lrow + 64] = b1.w * wsq[3] * reb1;
    __syncthreads();
#pragma unroll
    for (int k = 0; k < 16; ++k) {
      float a[8], b[8];
      *(float4*)(a)     = *(const float4*)(&As[k][tn * 4]);
      *(float4*)(a + 4) = *(const float4*)(&As[k][64 + tn * 4]);
      *(float4*)(b)     = *(const float4*)(&Bs[k][tm * 4]);
      *(float4*)(b + 4) = *(const float4*)(&Bs[k][64 + tm * 4]);
#pragma unroll
      for (int i = 0; i < 8; ++i)
#pragma unroll
        for (int j = 0; j < 8; ++j) acc[i][j] += a[i] * b[j];
    }
  }
#pragma unroll
  for (int i = 0; i < 8; ++i) {
    int row = n0 + ((i < 4) ? (tn * 4 + i) : (64 + tn * 4 + i - 4));
    float* Crow = C + (size_t)row * N_EDGES + m0;
    float4 v0 = make_float4(acc[i][0] * 0.25f, acc[i][1] * 0.25f,
                            acc[i][2] * 0.25f, acc[i][3] * 0.25f);
    float4 v1 = make_float4(acc[i][4] * 0.25f, acc[i][5] * 0.25f,
                            acc[i][6] * 0.25f, acc[i][7] * 0.25f);
    *(float4*)(Crow + tm * 4)      = v0;
    *(float4*)(Crow + 64 + tm * 4) = v1;
  }
}

// ---------------- K7: mask existing incidences ----------------
__global__ void maskset_k(const int* __restrict__ V, const int* __restrict__ E,
                          float* __restrict__ S) {
  int i = blockIdx.x * blockDim.x + threadIdx.x;
  if (i < NNZ) S[(size_t)V[i] * N_EDGES + E[i]] = -1e9f;
}

// ---------------- K8: 8192-bin histogram over S ----------------
__global__ __launch_bounds__(256) void hist_k(const float4* __restrict__ S4,
                                              unsigned* __restrict__ ghist) {
  __shared__ unsigned hh[NBINS];
  for (int i = threadIdx.x; i < NBINS; i += 256) hh[i] = 0;
  __syncthreads();
  int stride = gridDim.x * blockDim.x;
  for (int i = blockIdx.x * blockDim.x + threadIdx.x; i < S_TOTAL / 4; i += stride) {
    float4 v = S4[i];
    float vv[4] = {v.x, v.y, v.z, v.w};
#pragma unroll
    for (int c = 0; c < 4; ++c) {
      float bf = fminf(fmaxf((vv[c] + 1.0f) * 4096.0f, 0.0f), (float)(NBINS - 1));
      atomicAdd(&hh[(int)bf], 1u);
    }
  }
  __syncthreads();
  for (int i = threadIdx.x; i < NBINS; i += 256)
    if (hh[i]) atomicAdd(&ghist[i], hh[i]);
}

// ---------------- K9: screening threshold, 160 bins (0.039) below the k-th bin ----------------
__global__ __launch_bounds__(1024) void thresh_k(const unsigned* __restrict__ hist,
                                                 float* __restrict__ T_lo) {
  __shared__ unsigned suff[1024];
  int t = threadIdx.x;
  const int G = NBINS / 1024;
  int b0 = t * G;
  unsigned s = 0;
  for (int j = 0; j < G; ++j) s += hist[b0 + j];
  unsigned v = s;
  suff[t] = v; __syncthreads();
  for (int o = 1; o < 1024; o <<= 1) {
    unsigned add = (t + o < 1024) ? suff[t + o] : 0u;
    __syncthreads();
    v += add; suff[t] = v;
    __syncthreads();
  }
  unsigned above = (t < 1023) ? suff[t + 1] : 0u;
  if (above < (unsigned)K_TOP && suff[t] >= (unsigned)K_TOP) {
    unsigned running = above;
    int B = b0;
    for (int b = b0 + G - 1; b >= b0; --b) {
      running += hist[b];
      if (running >= (unsigned)K_TOP) { B = b; break; }
    }
    B = max(B, SLACK_BINS);
    *T_lo = (float)(B - SLACK_BINS) * (1.0f / 4096.0f) - 1.0f;
  }
}

// ---------------- K10: compact candidate positions >= T_lo ----------------
__global__ void collect_k(const float4* __restrict__ S4, const float* __restrict__ T_lo_p,
                          unsigned* __restrict__ counter, int* __restrict__ ci) {
  float T = *T_lo_p;
  int stride = gridDim.x * blockDim.x;
  for (int i = blockIdx.x * blockDim.x + threadIdx.x; i < S_TOTAL / 4; i += stride) {
    float4 v = S4[i];
    float vv[4] = {v.x, v.y, v.z, v.w};
#pragma unroll
    for (int c = 0; c < 4; ++c) {
      if (vv[c] >= T) {
        unsigned j = atomicAdd(counter, 1u);
        if (j < CAP2) ci[j] = i * 4 + c;
      }
    }
  }
}

// ---------------- K11: FULL f64 rescore from raw inputs (1 wave / candidate) ----------------
// Recomputes the edge mean in f64 from the index-sorted CSR, then the 4-head
// cosine in f64 — ranking is by true values, independent of the f32 screen.
__global__ __launch_bounds__(256) void rescore_k(const float* __restrict__ X,
                                                 const float* __restrict__ W,
                                                 const int* __restrict__ V,
                                                 const int* __restrict__ cnt,
                                                 const int* __restrict__ offs,
                                                 const int* __restrict__ bucket,
                                                 const int* __restrict__ ci,
                                                 const unsigned* __restrict__ counter,
                                                 double* __restrict__ cv) {
  int C = (int)min(*counter, (unsigned)CAP2);
  int wave = threadIdx.x >> 6, lane = threadIdx.x & 63;
  int j = blockIdx.x * 4 + wave;
  if (j >= C) return;
  int pos = ci[j];
  int n = pos >> 13;        // / 8192
  int m = pos & 8191;
  int deg = cnt[m], off = offs[m];
  int nmem = min(deg, 512);
  // f64 edge mean, members in ascending original-index order (== np.add.at order)
  double e0 = 0.0, e1 = 0.0;
  for (int q = 0; q < nmem; ++q) {
    const float* xv = X + (size_t)V[bucket[off + q]] * EMB;
    e0 += (double)xv[lane];
    e1 += (double)xv[lane + 64];
  }
  double dd = fmax((double)deg, 1.0);
  e0 /= dd; e1 /= dd;
  const float* xr = X + (size_t)n * EMB;
  double x0 = (double)xr[lane], x1 = (double)xr[lane + 64];
  double s = 0.0;
  for (int h = 0; h < NHEAD; ++h) {
    const float* wr = W + h * EMB;
    double w0 = (double)wr[lane], w1 = (double)wr[lane + 64];
    double xw0 = x0 * w0, xw1 = x1 * w1;
    double ew0 = e0 * w0, ew1 = e1 * w1;
    double an = xw0 * xw0 + xw1 * xw1;
    double ae = ew0 * ew0 + ew1 * ew1;
    double dt = xw0 * ew0 + xw1 * ew1;
    for (int o = 32; o > 0; o >>= 1) {
      an += __shfl_down(an, o, 64);
      ae += __shfl_down(ae, o, 64);
      dt += __shfl_down(dt, o, 64);
    }
    if (lane == 0) {
      double Nn = fmax(sqrt(an), 1e-6);
      double Ne = fmax(sqrt(ae), 1e-6);
      s += dt / (Nn * Ne);
    }
  }
  if (lane == 0) cv[j] = s * 0.25;
}

// ---------------- K12: exact stable rank; write top-k masks ----------------
__global__ __launch_bounds__(256) void select_k(const double* __restrict__ cv,
                                                const int* __restrict__ ci,
                                                const unsigned* __restrict__ counter,
                                                const float* __restrict__ P,
                                                float* __restrict__ out) {
  __shared__ double sv[256];
  __shared__ int    si[256];
  int C = (int)min(*counter, (unsigned)CAP2);
  if (blockIdx.x * 256 >= C) return;   // uniform early-exit before any barrier
  int j = blockIdx.x * 256 + threadIdx.x;
  bool act = (j < C);
  double vj = act ? cv[j] : 0.0;
  int    ij = act ? ci[j] : 0;
  int rank = 0;
  for (int base = 0; base < C; base += 256) {
    int t = base + threadIdx.x;
    if (t < C) { sv[threadIdx.x] = cv[t]; si[threadIdx.x] = ci[t]; }
    __syncthreads();
    int lim = min(256, C - base);
    if (act) {
      for (int q = 0; q < lim; ++q) {
        double vc = sv[q]; int ic = si[q];
        if (vc > vj || (vc == vj && ic < ij)) ++rank;  // top_k tie-break: lower idx first
      }
    }
    __syncthreads();
  }
  if (act && rank < K_TOP) {
    unsigned pos = (unsigned)ij;
    out[pos] = mask_val(P[pos], pos);
  }
}

// ---------------- K13: H positions (the (V,E) pairs) ----------------
__global__ void scatterH_k(const int* __restrict__ V, const int* __restrict__ E,
                           const float* __restrict__ P, float* __restrict__ out) {
  int i = blockIdx.x * blockDim.x + threadIdx.x;
  if (i >= NNZ) return;
  unsigned pos = (unsigned)V[i] * (unsigned)N_EDGES + (unsigned)E[i];
  out[pos] = mask_val(P[pos], pos);
}

extern "C" void kernel_launch(void* const* d_in, const int* in_sizes, int n_in,
                              void* d_out, int out_size, void* d_ws, size_t ws_size,
                              hipStream_t stream) {
  const float* X = (const float*)d_in[0];   // f32
  // d_in[1] = H (unused: nonzeros are exactly the (V,E) pairs)
  const int*   V = (const int*)d_in[2];
  const int*   E = (const int*)d_in[3];
  const float* P = (const float*)d_in[4];   // f32
  const float* W = (const float*)d_in[5];   // f32
  float* S = (float*)d_out;                 // out buffer doubles as the score matrix

  // ws layout — ~6.1 MB
  char* w = (char*)d_ws;
  int*      cnt      = (int*)(w + 0);            // 32 KB
  int*      offs     = (int*)(w + 32768);        // 32 KB
  int*      cursor   = (int*)(w + 65536);        // 32 KB
  int*      bucket   = (int*)(w + 98304);        // 256 KB -> 360448
  unsigned* hist     = (unsigned*)(w + 360448);  // 32 KB  -> 393216
  unsigned* counter  = (unsigned*)(w + 393216);  // 4 B
  float*    T_lo     = (float*)(w + 393220);     // 4 B
  int*      cand_idx = (int*)(w + 393472);       // 512 KB -> 917760
  double*   cand_val = (double*)(w + 917760);    // 1 MB   -> 1966336 (8B aligned)
  float*    nn       = (float*)(w + 1966336);    // 64 KB  -> 2031872
  float*    ne       = (float*)(w + 2031872);    // 128 KB -> 2162944
  float*    eX       = (float*)(w + 2162944);    // 4 MB   -> 6357248

  hipMemsetAsync(cnt,     0, 32768, stream);
  hipMemsetAsync(cursor,  0, 32768, stream);
  hipMemsetAsync(hist,    0, NBINS * 4, stream);
  hipMemsetAsync(counter, 0, 8, stream);         // zeroes counter + T_lo

  count_k   <<<NNZ / 256, 256, 0, stream>>>(E, cnt);
  scan_k    <<<1, 1024, 0, stream>>>(cnt, offs);
  scatter_k <<<NNZ / 256, 256, 0, stream>>>(E, offs, cursor, bucket);
  edge_k    <<<N_EDGES, 128, 0, stream>>>(X, V, cnt, offs, bucket, W, eX, ne);
  node_k    <<<N_CODES, 128, 0, stream>>>(X, W, nn);
  gemm_fused<<<dim3(N_EDGES / 128, N_CODES / 128), 256, 0, stream>>>(X, eX, W, nn, ne, S);
  maskset_k <<<NNZ / 256, 256, 0, stream>>>(V, E, S);
  hist_k    <<<512, 256, 0, stream>>>((const float4*)S, hist);
  thresh_k  <<<1, 1024, 0, stream>>>(hist, T_lo);
  collect_k <<<1024, 256, 0, stream>>>((const float4*)S, T_lo, counter, cand_idx);
  rescore_k <<<CAP2 / 4, 256, 0, stream>>>(X, W, V, cnt, offs, bucket,
                                           cand_idx, counter, cand_val);
  hipMemsetAsync(d_out, 0, (size_t)S_TOTAL * 4, stream);
  select_k  <<<CAP2 / 256, 256, 0, stream>>>(cand_val, cand_idx, counter, P, S);
  scatterH_k<<<NNZ / 256, 256, 0, stream>>>(V, E, P, S);
}

// Round 6
// 1543.581 us; speedup vs baseline: 2.5287x; 2.5287x over previous
//
#include <hip/hip_runtime.h>
#include <math.h>

#define N_CODES 4096
#define N_EDGES 8192
#define EMB     128
#define NHEAD   4
#define NNZ     65536
#define K_TOP   6553            // int(0.1 * 65536)
#define S_TOTAL 33554432        // 4096 * 8192
#define NBINS   8192            // 32 KB LDS histogram
#define CAP2    131072          // candidate cap (pool now ~13k; cap is safety)
#define SLACK_BINS 8            // 1.95e-3 screening slack ≈ 1500x the f32 GEMM noise

// ---------------- threefry2x32, JAX partitionable scheme, 32-bit path ----------------
// bits[idx] = w0 ^ w1 of threefry2x32(key=(0,42), ctr=(hi32(idx), lo32(idx)))
__device__ __forceinline__ unsigned rotl32(unsigned v, int r) {
  return (v << r) | (v >> (32 - r));
}

__device__ float jax_u42(unsigned pos) {
  const unsigned ks0 = 0u, ks1 = 42u, ks2 = 0x1BD11BDAu ^ 0u ^ 42u;
  unsigned x0 = 0u  + ks0;   // counts_hi + ks0
  unsigned x1 = pos + ks1;   // counts_lo + ks1
#define TFR(r) { x0 += x1; x1 = rotl32(x1, (r)); x1 ^= x0; }
  TFR(13) TFR(15) TFR(26) TFR(6)   x0 += ks1; x1 += ks2 + 1u;
  TFR(17) TFR(29) TFR(16) TFR(24)  x0 += ks2; x1 += ks0 + 2u;
  TFR(13) TFR(15) TFR(26) TFR(6)   x0 += ks0; x1 += ks1 + 3u;
  TFR(17) TFR(29) TFR(16) TFR(24)  x0 += ks1; x1 += ks2 + 4u;
  TFR(13) TFR(15) TFR(26) TFR(6)   x0 += ks2; x1 += ks0 + 5u;
#undef TFR
  unsigned bits = x0 ^ x1;   // 32-bit partitionable path XORs the two output words
  unsigned fb = (bits >> 9) | 0x3f800000u;
  float f = __uint_as_float(fb) - 1.0f;
  const float minv = 1e-6f;
  const float maxv = (float)(1.0 - 1e-6);
  float u = f * (maxv - minv) + minv;
  return fmaxf(minv, u);
}

__device__ float mask_val(float p, unsigned pos) {
  float u = jax_u42(pos);
  float l = (logf(p) - log1pf(-p) + logf(u) - log1pf(-u)) * 2.0f; // /TEMP, TEMP=0.5
  return 1.0f / (1.0f + expf(-l));
}

// ---------------- K1: per-edge counts ----------------
__global__ void count_k(const int* __restrict__ E, int* __restrict__ cnt) {
  int i = blockIdx.x * blockDim.x + threadIdx.x;
  if (i < NNZ) atomicAdd(&cnt[E[i]], 1);
}

// ---------------- K2: exclusive scan of 8192 counts ----------------
__global__ __launch_bounds__(1024) void scan_k(const int* __restrict__ cnt,
                                               int* __restrict__ offs) {
  __shared__ int part[1024];
  int t = threadIdx.x;
  int local[8]; int s = 0;
  for (int j = 0; j < 8; ++j) { local[j] = cnt[t * 8 + j]; s += local[j]; }
  part[t] = s; __syncthreads();
  int v = s;
  for (int o = 1; o < 1024; o <<= 1) {
    int add = (t >= o) ? part[t - o] : 0;
    __syncthreads();
    v += add; part[t] = v;
    __syncthreads();
  }
  int base = v - s;
  for (int j = 0; j < 8; ++j) { offs[t * 8 + j] = base; base += local[j]; }
}

// ---------------- K3: bucket scatter (CSR) ----------------
__global__ void scatter_k(const int* __restrict__ E, const int* __restrict__ offs,
                          int* __restrict__ cursor, int* __restrict__ bucket) {
  int i = blockIdx.x * blockDim.x + threadIdx.x;
  if (i < NNZ) {
    int e = E[i];
    int p = atomicAdd(&cursor[e], 1);
    bucket[offs[e] + p] = i;
  }
}

// ---------------- K4: sort CSR lists, edge means eX (f32) + recip norms; write sorted back ----------------
__global__ __launch_bounds__(128) void edge_k(const float* __restrict__ X,
                                              const int* __restrict__ V,
                                              const int* __restrict__ cnt,
                                              const int* __restrict__ offs,
                                              int* __restrict__ bucket,
                                              const float* __restrict__ W,
                                              float* __restrict__ eX,
                                              float* __restrict__ ne) {
  __shared__ int lst[512];
  __shared__ float red[2];
  int m = blockIdx.x, t = threadIdx.x;
  int deg = cnt[m], off = offs[m];
  int n = min(deg, 512);
  for (int j = t; j < n; j += 128) lst[j] = bucket[off + j];
  __syncthreads();
  if (t == 0 && n > 1) {             // ascending-index order == np.add.at order
    for (int a = 1; a < n; ++a) {
      int key = lst[a]; int b = a - 1;
      while (b >= 0 && lst[b] > key) { lst[b + 1] = lst[b]; --b; }
      lst[b + 1] = key;
    }
  }
  __syncthreads();
  for (int j = t; j < n; j += 128) bucket[off + j] = lst[j];  // sorted CSR for rescore
  float s = 0.f;
  for (int j = 0; j < n; ++j) s += X[(size_t)V[lst[j]] * EMB + t];
  float eXd = s / fmaxf((float)deg, 1.0f);
  eX[(size_t)m * EMB + t] = eXd;
  int lane = t & 63, wv = t >> 6;
  for (int h = 0; h < NHEAD; ++h) {
    float val = eXd * W[h * EMB + t];
    float ss = val * val;
    for (int o = 32; o > 0; o >>= 1) ss += __shfl_down(ss, o, 64);
    if (lane == 0) red[wv] = ss;
    __syncthreads();
    if (t == 0) ne[m * NHEAD + h] = 1.0f / fmaxf(sqrtf(red[0] + red[1]), 1e-6f);
    __syncthreads();
  }
}

// ---------------- K5: node recip head-norms ----------------
__global__ __launch_bounds__(128) void node_k(const float* __restrict__ X,
                                              const float* __restrict__ W,
                                              float* __restrict__ nn) {
  __shared__ float red[2];
  int n = blockIdx.x, t = threadIdx.x;
  float xd = X[(size_t)n * EMB + t];
  int lane = t & 63, wv = t >> 6;
  for (int h = 0; h < NHEAD; ++h) {
    float val = xd * W[h * EMB + t];
    float ss = val * val;
    for (int o = 32; o > 0; o >>= 1) ss += __shfl_down(ss, o, 64);
    if (lane == 0) red[wv] = ss;
    __syncthreads();
    if (t == 0) nn[n * NHEAD + h] = 1.0f / fmaxf(sqrtf(red[0] + red[1]), 1e-6f);
    __syncthreads();
  }
}

// ---------------- K6: fused-normalization fp32 GEMM (screening only) ----------------
__global__ __launch_bounds__(256) void gemm_fused(const float* __restrict__ X,
                                                  const float* __restrict__ eX,
                                                  const float* __restrict__ W,
                                                  const float* __restrict__ nn,
                                                  const float* __restrict__ ne,
                                                  float* __restrict__ C) {
  __shared__ float As[16][132];
  __shared__ float Bs[16][132];
  const int tid  = threadIdx.x;
  const int n0   = blockIdx.y * 128;
  const int m0   = blockIdx.x * 128;
  const int tn   = tid & 15;
  const int tm   = tid >> 4;
  const int lrow = tid >> 2;
  const int lc   = (tid & 3) << 2;

  float acc[8][8];
#pragma unroll
  for (int i = 0; i < 8; ++i)
#pragma unroll
    for (int j = 0; j < 8; ++j) acc[i][j] = 0.f;

  for (int k0 = 0; k0 < 512; k0 += 16) {
    const int h  = k0 >> 7;
    const int d0 = (k0 & 127) + lc;
    float4 a0 = *(const float4*)(X  + (size_t)(n0 + lrow)      * EMB + d0);
    float4 a1 = *(const float4*)(X  + (size_t)(n0 + lrow + 64) * EMB + d0);
    float4 b0 = *(const float4*)(eX + (size_t)(m0 + lrow)      * EMB + d0);
    float4 b1 = *(const float4*)(eX + (size_t)(m0 + lrow + 64) * EMB + d0);
    float rna0 = nn[(n0 + lrow)      * NHEAD + h];
    float rna1 = nn[(n0 + lrow + 64) * NHEAD + h];
    float reb0 = ne[(m0 + lrow)      * NHEAD + h];
    float reb1 = ne[(m0 + lrow + 64) * NHEAD + h];
    float wsq[4];
#pragma unroll
    for (int c = 0; c < 4; ++c) {
      float wv = W[h * EMB + d0 + c];
      wsq[c] = wv * wv;
    }
    __syncthreads();
    As[lc + 0][lrow] = a0.x * rna0; As[lc + 1][lrow] = a0.y * rna0;
    As[lc + 2][lrow] = a0.z * rna0; As[lc + 3][lrow] = a0.w * rna0;
    As[lc + 0][lrow + 64] = a1.x * rna1; As[lc + 1][lrow + 64] = a1.y * rna1;
    As[lc + 2][lrow + 64] = a1.z * rna1; As[lc + 3][lrow + 64] = a1.w * rna1;
    Bs[lc + 0][lrow] = b0.x * wsq[0] * reb0; Bs[lc + 1][lrow] = b0.y * wsq[1] * reb0;
    Bs[lc + 2][lrow] = b0.z * wsq[2] * reb0; Bs[lc + 3][lrow] = b0.w * wsq[3] * reb0;
    Bs[lc + 0][lrow + 64] = b1.x * wsq[0] * reb1; Bs[lc + 1][lrow + 64] = b1.y * wsq[1] * reb1;
    Bs[lc + 2][lrow + 64] = b1.z * wsq[2] * reb1; Bs[lc + 3][lrow + 64] = b1.w * wsq[3] * reb1;
    __syncthreads();
#pragma unroll
    for (int k = 0; k < 16; ++k) {
      float a[8], b[8];
      *(float4*)(a)     = *(const float4*)(&As[k][tn * 4]);
      *(float4*)(a + 4) = *(const float4*)(&As[k][64 + tn * 4]);
      *(float4*)(b)     = *(const float4*)(&Bs[k][tm * 4]);
      *(float4*)(b + 4) = *(const float4*)(&Bs[k][64 + tm * 4]);
#pragma unroll
      for (int i = 0; i < 8; ++i)
#pragma unroll
        for (int j = 0; j < 8; ++j) acc[i][j] += a[i] * b[j];
    }
  }
#pragma unroll
  for (int i = 0; i < 8; ++i) {
    int row = n0 + ((i < 4) ? (tn * 4 + i) : (64 + tn * 4 + i - 4));
    float* Crow = C + (size_t)row * N_EDGES + m0;
    float4 v0 = make_float4(acc[i][0] * 0.25f, acc[i][1] * 0.25f,
                            acc[i][2] * 0.25f, acc[i][3] * 0.25f);
    float4 v1 = make_float4(acc[i][4] * 0.25f, acc[i][5] * 0.25f,
                            acc[i][6] * 0.25f, acc[i][7] * 0.25f);
    *(float4*)(Crow + tm * 4)      = v0;
    *(float4*)(Crow + 64 + tm * 4) = v1;
  }
}

// ---------------- K7: mask existing incidences ----------------
__global__ void maskset_k(const int* __restrict__ V, const int* __restrict__ E,
                          float* __restrict__ S) {
  int i = blockIdx.x * blockDim.x + threadIdx.x;
  if (i < NNZ) S[(size_t)V[i] * N_EDGES + E[i]] = -1e9f;
}

// ---------------- K8: 8192-bin histogram over S ----------------
__global__ __launch_bounds__(256) void hist_k(const float4* __restrict__ S4,
                                              unsigned* __restrict__ ghist) {
  __shared__ unsigned hh[NBINS];
  for (int i = threadIdx.x; i < NBINS; i += 256) hh[i] = 0;
  __syncthreads();
  int stride = gridDim.x * blockDim.x;
  for (int i = blockIdx.x * blockDim.x + threadIdx.x; i < S_TOTAL / 4; i += stride) {
    float4 v = S4[i];
    float vv[4] = {v.x, v.y, v.z, v.w};
#pragma unroll
    for (int c = 0; c < 4; ++c) {
      float bf = fminf(fmaxf((vv[c] + 1.0f) * 4096.0f, 0.0f), (float)(NBINS - 1));
      atomicAdd(&hh[(int)bf], 1u);
    }
  }
  __syncthreads();
  for (int i = threadIdx.x; i < NBINS; i += 256)
    if (hh[i]) atomicAdd(&ghist[i], hh[i]);
}

// ---------------- K9: screening threshold, SLACK_BINS below the k-th bin ----------------
__global__ __launch_bounds__(1024) void thresh_k(const unsigned* __restrict__ hist,
                                                 float* __restrict__ T_lo) {
  __shared__ unsigned suff[1024];
  int t = threadIdx.x;
  const int G = NBINS / 1024;
  int b0 = t * G;
  unsigned s = 0;
  for (int j = 0; j < G; ++j) s += hist[b0 + j];
  unsigned v = s;
  suff[t] = v; __syncthreads();
  for (int o = 1; o < 1024; o <<= 1) {
    unsigned add = (t + o < 1024) ? suff[t + o] : 0u;
    __syncthreads();
    v += add; suff[t] = v;
    __syncthreads();
  }
  unsigned above = (t < 1023) ? suff[t + 1] : 0u;
  if (above < (unsigned)K_TOP && suff[t] >= (unsigned)K_TOP) {
    unsigned running = above;
    int B = b0;
    for (int b = b0 + G - 1; b >= b0; --b) {
      running += hist[b];
      if (running >= (unsigned)K_TOP) { B = b; break; }
    }
    B = max(B, SLACK_BINS);
    *T_lo = (float)(B - SLACK_BINS) * (1.0f / 4096.0f) - 1.0f;
  }
}

// ---------------- K10: compact candidate positions >= T_lo ----------------
__global__ void collect_k(const float4* __restrict__ S4, const float* __restrict__ T_lo_p,
                          unsigned* __restrict__ counter, int* __restrict__ ci) {
  float T = *T_lo_p;
  int stride = gridDim.x * blockDim.x;
  for (int i = blockIdx.x * blockDim.x + threadIdx.x; i < S_TOTAL / 4; i += stride) {
    float4 v = S4[i];
    float vv[4] = {v.x, v.y, v.z, v.w};
#pragma unroll
    for (int c = 0; c < 4; ++c) {
      if (vv[c] >= T) {
        unsigned j = atomicAdd(counter, 1u);
        if (j < CAP2) ci[j] = i * 4 + c;
      }
    }
  }
}

// ---------------- K11: FULL f64 rescore from raw inputs (1 wave / candidate) ----------------
__global__ __launch_bounds__(256) void rescore_k(const float* __restrict__ X,
                                                 const float* __restrict__ W,
                                                 const int* __restrict__ V,
                                                 const int* __restrict__ cnt,
                                                 const int* __restrict__ offs,
                                                 const int* __restrict__ bucket,
                                                 const int* __restrict__ ci,
                                                 const unsigned* __restrict__ counter,
                                                 double* __restrict__ cv) {
  int C = (int)min(*counter, (unsigned)CAP2);
  int wave = threadIdx.x >> 6, lane = threadIdx.x & 63;
  int j = blockIdx.x * 4 + wave;
  if (j >= C) return;
  int pos = ci[j];
  int n = pos >> 13;        // / 8192
  int m = pos & 8191;
  int deg = cnt[m], off = offs[m];
  int nmem = min(deg, 512);
  double e0 = 0.0, e1 = 0.0;
  for (int q = 0; q < nmem; ++q) {
    const float* xv = X + (size_t)V[bucket[off + q]] * EMB;
    e0 += (double)xv[lane];
    e1 += (double)xv[lane + 64];
  }
  double dd = fmax((double)deg, 1.0);
  e0 /= dd; e1 /= dd;
  const float* xr = X + (size_t)n * EMB;
  double x0 = (double)xr[lane], x1 = (double)xr[lane + 64];
  double s = 0.0;
  for (int h = 0; h < NHEAD; ++h) {
    const float* wr = W + h * EMB;
    double w0 = (double)wr[lane], w1 = (double)wr[lane + 64];
    double xw0 = x0 * w0, xw1 = x1 * w1;
    double ew0 = e0 * w0, ew1 = e1 * w1;
    double an = xw0 * xw0 + xw1 * xw1;
    double ae = ew0 * ew0 + ew1 * ew1;
    double dt = xw0 * ew0 + xw1 * ew1;
    for (int o = 32; o > 0; o >>= 1) {
      an += __shfl_down(an, o, 64);
      ae += __shfl_down(ae, o, 64);
      dt += __shfl_down(dt, o, 64);
    }
    if (lane == 0) {
      double Nn = fmax(sqrt(an), 1e-6);
      double Ne = fmax(sqrt(ae), 1e-6);
      s += dt / (Nn * Ne);
    }
  }
  if (lane == 0) cv[j] = s * 0.25;
}

// ---------------- K12: exact stable rank; write top-k masks ----------------
__global__ __launch_bounds__(256) void select_k(const double* __restrict__ cv,
                                                const int* __restrict__ ci,
                                                const unsigned* __restrict__ counter,
                                                const float* __restrict__ P,
                                                float* __restrict__ out) {
  __shared__ double sv[256];
  __shared__ int    si[256];
  int C = (int)min(*counter, (unsigned)CAP2);
  if (blockIdx.x * 256 >= C) return;   // uniform early-exit before any barrier
  int j = blockIdx.x * 256 + threadIdx.x;
  bool act = (j < C);
  double vj = act ? cv[j] : 0.0;
  int    ij = act ? ci[j] : 0;
  int rank = 0;
  for (int base = 0; base < C; base += 256) {
    int t = base + threadIdx.x;
    if (t < C) { sv[threadIdx.x] = cv[t]; si[threadIdx.x] = ci[t]; }
    __syncthreads();
    int lim = min(256, C - base);
    if (act) {
      for (int q = 0; q < lim; ++q) {
        double vc = sv[q]; int ic = si[q];
        if (vc > vj || (vc == vj && ic < ij)) ++rank;  // top_k tie-break: lower idx first
      }
    }
    __syncthreads();
  }
  if (act && rank < K_TOP) {
    unsigned pos = (unsigned)ij;
    out[pos] = mask_val(P[pos], pos);
  }
}

// ---------------- K13: H positions (the (V,E) pairs) ----------------
__global__ void scatterH_k(const int* __restrict__ V, const int* __restrict__ E,
                           const float* __restrict__ P, float* __restrict__ out) {
  int i = blockIdx.x * blockDim.x + threadIdx.x;
  if (i >= NNZ) return;
  unsigned pos = (unsigned)V[i] * (unsigned)N_EDGES + (unsigned)E[i];
  out[pos] = mask_val(P[pos], pos);
}

extern "C" void kernel_launch(void* const* d_in, const int* in_sizes, int n_in,
                              void* d_out, int out_size, void* d_ws, size_t ws_size,
                              hipStream_t stream) {
  const float* X = (const float*)d_in[0];   // f32
  // d_in[1] = H (unused: nonzeros are exactly the (V,E) pairs)
  const int*   V = (const int*)d_in[2];
  const int*   E = (const int*)d_in[3];
  const float* P = (const float*)d_in[4];   // f32
  const float* W = (const float*)d_in[5];   // f32
  float* S = (float*)d_out;                 // out buffer doubles as the score matrix

  // ws layout — ~6.1 MB
  char* w = (char*)d_ws;
  int*      cnt      = (int*)(w + 0);            // 32 KB
  int*      offs     = (int*)(w + 32768);        // 32 KB
  int*      cursor   = (int*)(w + 65536);        // 32 KB
  int*      bucket   = (int*)(w + 98304);        // 256 KB -> 360448
  unsigned* hist     = (unsigned*)(w + 360448);  // 32 KB  -> 393216
  unsigned* counter  = (unsigned*)(w + 393216);  // 4 B
  float*    T_lo     = (float*)(w + 393220);     // 4 B
  int*      cand_idx = (int*)(w + 393472);       // 512 KB -> 917760
  double*   cand_val = (double*)(w + 917760);    // 1 MB   -> 1966336 (8B aligned)
  float*    nn       = (float*)(w + 1966336);    // 64 KB  -> 2031872
  float*    ne       = (float*)(w + 2031872);    // 128 KB -> 2162944
  float*    eX       = (float*)(w + 2162944);    // 4 MB   -> 6357248

  hipMemsetAsync(cnt,     0, 32768, stream);
  hipMemsetAsync(cursor,  0, 32768, stream);
  hipMemsetAsync(hist,    0, NBINS * 4, stream);
  hipMemsetAsync(counter, 0, 8, stream);         // zeroes counter + T_lo

  count_k   <<<NNZ / 256, 256, 0, stream>>>(E, cnt);
  scan_k    <<<1, 1024, 0, stream>>>(cnt, offs);
  scatter_k <<<NNZ / 256, 256, 0, stream>>>(E, offs, cursor, bucket);
  edge_k    <<<N_EDGES, 128, 0, stream>>>(X, V, cnt, offs, bucket, W, eX, ne);
  node_k    <<<N_CODES, 128, 0, stream>>>(X, W, nn);
  gemm_fused<<<dim3(N_EDGES / 128, N_CODES / 128), 256, 0, stream>>>(X, eX, W, nn, ne, S);
  maskset_k <<<NNZ / 256, 256, 0, stream>>>(V, E, S);
  hist_k    <<<512, 256, 0, stream>>>((const float4*)S, hist);
  thresh_k  <<<1, 1024, 0, stream>>>(hist, T_lo);
  collect_k <<<1024, 256, 0, stream>>>((const float4*)S, T_lo, counter, cand_idx);
  rescore_k <<<CAP2 / 4, 256, 0, stream>>>(X, W, V, cnt, offs, bucket,
                                           cand_idx, counter, cand_val);
  hipMemsetAsync(d_out, 0, (size_t)S_TOTAL * 4, stream);
  select_k  <<<CAP2 / 256, 256, 0, stream>>>(cand_val, cand_idx, counter, P, S);
  scatterH_k<<<NNZ / 256, 256, 0, stream>>>(V, E, P, S);
}

// Round 8
// 896.432 us; speedup vs baseline: 4.3542x; 1.7219x over previous
//
#include <hip/hip_runtime.h>
#include <math.h>

#define N_CODES 4096
#define N_EDGES 8192
#define EMB     128
#define NHEAD   4
#define NNZ     65536
#define K_TOP   6553            // int(0.1 * 65536)
#define S_TOTAL 33554432        // 4096 * 8192
#define NBINS   8192            // 32 KB LDS histogram
#define CAP2    131072          // candidate cap (pool ~30k at 8-bin slack)
#define SLACK_BINS 8            // 1.95e-3 screening slack ≈ 1000x the f32 GEMM noise
#define TIE_CAP 1024

// ---------------- threefry2x32, JAX partitionable scheme, 32-bit path ----------------
// bits[idx] = w0 ^ w1 of threefry2x32(key=(0,42), ctr=(hi32(idx), lo32(idx)))
__device__ __forceinline__ unsigned rotl32(unsigned v, int r) {
  return (v << r) | (v >> (32 - r));
}

__device__ float jax_u42(unsigned pos) {
  const unsigned ks0 = 0u, ks1 = 42u, ks2 = 0x1BD11BDAu ^ 0u ^ 42u;
  unsigned x0 = 0u  + ks0;
  unsigned x1 = pos + ks1;
#define TFR(r) { x0 += x1; x1 = rotl32(x1, (r)); x1 ^= x0; }
  TFR(13) TFR(15) TFR(26) TFR(6)   x0 += ks1; x1 += ks2 + 1u;
  TFR(17) TFR(29) TFR(16) TFR(24)  x0 += ks2; x1 += ks0 + 2u;
  TFR(13) TFR(15) TFR(26) TFR(6)   x0 += ks0; x1 += ks1 + 3u;
  TFR(17) TFR(29) TFR(16) TFR(24)  x0 += ks1; x1 += ks2 + 4u;
  TFR(13) TFR(15) TFR(26) TFR(6)   x0 += ks2; x1 += ks0 + 5u;
#undef TFR
  unsigned bits = x0 ^ x1;
  unsigned fb = (bits >> 9) | 0x3f800000u;
  float f = __uint_as_float(fb) - 1.0f;
  const float minv = 1e-6f;
  const float maxv = (float)(1.0 - 1e-6);
  float u = f * (maxv - minv) + minv;
  return fmaxf(minv, u);
}

__device__ float mask_val(float p, unsigned pos) {
  float u = jax_u42(pos);
  float l = (logf(p) - log1pf(-p) + logf(u) - log1pf(-u)) * 2.0f; // /TEMP, TEMP=0.5
  return 1.0f / (1.0f + expf(-l));
}

// f64 -> u64 monotone key (larger double <=> larger key)
__device__ __forceinline__ unsigned long long f64key(double v) {
  long long b = __double_as_longlong(v);
  return (b < 0) ? ~(unsigned long long)b
                 : ((unsigned long long)b | 0x8000000000000000ULL);
}

// ---------------- K1: per-edge counts ----------------
__global__ void count_k(const int* __restrict__ E, int* __restrict__ cnt) {
  int i = blockIdx.x * blockDim.x + threadIdx.x;
  if (i < NNZ) atomicAdd(&cnt[E[i]], 1);
}

// ---------------- K2: exclusive scan of 8192 counts ----------------
__global__ __launch_bounds__(1024) void scan_k(const int* __restrict__ cnt,
                                               int* __restrict__ offs) {
  __shared__ int part[1024];
  int t = threadIdx.x;
  int local[8]; int s = 0;
  for (int j = 0; j < 8; ++j) { local[j] = cnt[t * 8 + j]; s += local[j]; }
  part[t] = s; __syncthreads();
  int v = s;
  for (int o = 1; o < 1024; o <<= 1) {
    int add = (t >= o) ? part[t - o] : 0;
    __syncthreads();
    v += add; part[t] = v;
    __syncthreads();
  }
  int base = v - s;
  for (int j = 0; j < 8; ++j) { offs[t * 8 + j] = base; base += local[j]; }
}

// ---------------- K3: bucket scatter (CSR) ----------------
__global__ void scatter_k(const int* __restrict__ E, const int* __restrict__ offs,
                          int* __restrict__ cursor, int* __restrict__ bucket) {
  int i = blockIdx.x * blockDim.x + threadIdx.x;
  if (i < NNZ) {
    int e = E[i];
    int p = atomicAdd(&cursor[e], 1);
    bucket[offs[e] + p] = i;
  }
}

// ---------------- K4: sort CSR lists, edge means eX (f32) + recip norms ----------------
__global__ __launch_bounds__(128) void edge_k(const float* __restrict__ X,
                                              const int* __restrict__ V,
                                              const int* __restrict__ cnt,
                                              const int* __restrict__ offs,
                                              int* __restrict__ bucket,
                                              const float* __restrict__ W,
                                              float* __restrict__ eX,
                                              float* __restrict__ ne) {
  __shared__ int lst[512];
  __shared__ float red[2];
  int m = blockIdx.x, t = threadIdx.x;
  int deg = cnt[m], off = offs[m];
  int n = min(deg, 512);
  for (int j = t; j < n; j += 128) lst[j] = bucket[off + j];
  __syncthreads();
  if (t == 0 && n > 1) {             // ascending-index order == np.add.at order
    for (int a = 1; a < n; ++a) {
      int key = lst[a]; int b = a - 1;
      while (b >= 0 && lst[b] > key) { lst[b + 1] = lst[b]; --b; }
      lst[b + 1] = key;
    }
  }
  __syncthreads();
  for (int j = t; j < n; j += 128) bucket[off + j] = lst[j];  // sorted CSR for rescore
  float s = 0.f;
  for (int j = 0; j < n; ++j) s += X[(size_t)V[lst[j]] * EMB + t];
  float eXd = s / fmaxf((float)deg, 1.0f);
  eX[(size_t)m * EMB + t] = eXd;
  int lane = t & 63, wv = t >> 6;
  for (int h = 0; h < NHEAD; ++h) {
    float val = eXd * W[h * EMB + t];
    float ss = val * val;
    for (int o = 32; o > 0; o >>= 1) ss += __shfl_down(ss, o, 64);
    if (lane == 0) red[wv] = ss;
    __syncthreads();
    if (t == 0) ne[m * NHEAD + h] = 1.0f / fmaxf(sqrtf(red[0] + red[1]), 1e-6f);
    __syncthreads();
  }
}

// ---------------- K5: node recip head-norms ----------------
__global__ __launch_bounds__(128) void node_k(const float* __restrict__ X,
                                              const float* __restrict__ W,
                                              float* __restrict__ nn) {
  __shared__ float red[2];
  int n = blockIdx.x, t = threadIdx.x;
  float xd = X[(size_t)n * EMB + t];
  int lane = t & 63, wv = t >> 6;
  for (int h = 0; h < NHEAD; ++h) {
    float val = xd * W[h * EMB + t];
    float ss = val * val;
    for (int o = 32; o > 0; o >>= 1) ss += __shfl_down(ss, o, 64);
    if (lane == 0) red[wv] = ss;
    __syncthreads();
    if (t == 0) nn[n * NHEAD + h] = 1.0f / fmaxf(sqrtf(red[0] + red[1]), 1e-6f);
    __syncthreads();
  }
}

// ---------------- K6: fused-normalization fp32 GEMM (screening only) ----------------
__global__ __launch_bounds__(256) void gemm_fused(const float* __restrict__ X,
                                                  const float* __restrict__ eX,
                                                  const float* __restrict__ W,
                                                  const float* __restrict__ nn,
                                                  const float* __restrict__ ne,
                                                  float* __restrict__ C) {
  __shared__ float As[16][132];
  __shared__ float Bs[16][132];
  const int tid  = threadIdx.x;
  const int n0   = blockIdx.y * 128;
  const int m0   = blockIdx.x * 128;
  const int tn   = tid & 15;
  const int tm   = tid >> 4;
  const int lrow = tid >> 2;
  const int lc   = (tid & 3) << 2;

  float acc[8][8];
#pragma unroll
  for (int i = 0; i < 8; ++i)
#pragma unroll
    for (int j = 0; j < 8; ++j) acc[i][j] = 0.f;

  for (int k0 = 0; k0 < 512; k0 += 16) {
    const int h  = k0 >> 7;
    const int d0 = (k0 & 127) + lc;
    float4 a0 = *(const float4*)(X  + (size_t)(n0 + lrow)      * EMB + d0);
    float4 a1 = *(const float4*)(X  + (size_t)(n0 + lrow + 64) * EMB + d0);
    float4 b0 = *(const float4*)(eX + (size_t)(m0 + lrow)      * EMB + d0);
    float4 b1 = *(const float4*)(eX + (size_t)(m0 + lrow + 64) * EMB + d0);
    float rna0 = nn[(n0 + lrow)      * NHEAD + h];
    float rna1 = nn[(n0 + lrow + 64) * NHEAD + h];
    float reb0 = ne[(m0 + lrow)      * NHEAD + h];
    float reb1 = ne[(m0 + lrow + 64) * NHEAD + h];
    float wsq[4];
#pragma unroll
    for (int c = 0; c < 4; ++c) {
      float wv = W[h * EMB + d0 + c];
      wsq[c] = wv * wv;
    }
    __syncthreads();
    As[lc + 0][lrow] = a0.x * rna0; As[lc + 1][lrow] = a0.y * rna0;
    As[lc + 2][lrow] = a0.z * rna0; As[lc + 3][lrow] = a0.w * rna0;
    As[lc + 0][lrow + 64] = a1.x * rna1; As[lc + 1][lrow + 64] = a1.y * rna1;
    As[lc + 2][lrow + 64] = a1.z * rna1; As[lc + 3][lrow + 64] = a1.w * rna1;
    Bs[lc + 0][lrow] = b0.x * wsq[0] * reb0; Bs[lc + 1][lrow] = b0.y * wsq[1] * reb0;
    Bs[lc + 2][lrow] = b0.z * wsq[2] * reb0; Bs[lc + 3][lrow] = b0.w * wsq[3] * reb0;
    Bs[lc + 0][lrow + 64] = b1.x * wsq[0] * reb1; Bs[lc + 1][lrow + 64] = b1.y * wsq[1] * reb1;
    Bs[lc + 2][lrow + 64] = b1.z * wsq[2] * reb1; Bs[lc + 3][lrow + 64] = b1.w * wsq[3] * reb1;
    __syncthreads();
#pragma unroll
    for (int k = 0; k < 16; ++k) {
      float a[8], b[8];
      *(float4*)(a)     = *(const float4*)(&As[k][tn * 4]);
      *(float4*)(a + 4) = *(const float4*)(&As[k][64 + tn * 4]);
      *(float4*)(b)     = *(const float4*)(&Bs[k][tm * 4]);
      *(float4*)(b + 4) = *(const float4*)(&Bs[k][64 + tm * 4]);
#pragma unroll
      for (int i = 0; i < 8; ++i)
#pragma unroll
        for (int j = 0; j < 8; ++j) acc[i][j] += a[i] * b[j];
    }
  }
#pragma unroll
  for (int i = 0; i < 8; ++i) {
    int row = n0 + ((i < 4) ? (tn * 4 + i) : (64 + tn * 4 + i - 4));
    float* Crow = C + (size_t)row * N_EDGES + m0;
    float4 v0 = make_float4(acc[i][0] * 0.25f, acc[i][1] * 0.25f,
                            acc[i][2] * 0.25f, acc[i][3] * 0.25f);
    float4 v1 = make_float4(acc[i][4] * 0.25f, acc[i][5] * 0.25f,
                            acc[i][6] * 0.25f, acc[i][7] * 0.25f);
    *(float4*)(Crow + tm * 4)      = v0;
    *(float4*)(Crow + 64 + tm * 4) = v1;
  }
}

// ---------------- K7: mask existing incidences ----------------
__global__ void maskset_k(const int* __restrict__ V, const int* __restrict__ E,
                          float* __restrict__ S) {
  int i = blockIdx.x * blockDim.x + threadIdx.x;
  if (i < NNZ) S[(size_t)V[i] * N_EDGES + E[i]] = -1e9f;
}

// ---------------- K8: 8192-bin histogram over S ----------------
__global__ __launch_bounds__(256) void hist_k(const float4* __restrict__ S4,
                                              unsigned* __restrict__ ghist) {
  __shared__ unsigned hh[NBINS];
  for (int i = threadIdx.x; i < NBINS; i += 256) hh[i] = 0;
  __syncthreads();
  int stride = gridDim.x * blockDim.x;
  for (int i = blockIdx.x * blockDim.x + threadIdx.x; i < S_TOTAL / 4; i += stride) {
    float4 v = S4[i];
    float vv[4] = {v.x, v.y, v.z, v.w};
#pragma unroll
    for (int c = 0; c < 4; ++c) {
      float bf = fminf(fmaxf((vv[c] + 1.0f) * 4096.0f, 0.0f), (float)(NBINS - 1));
      atomicAdd(&hh[(int)bf], 1u);
    }
  }
  __syncthreads();
  for (int i = threadIdx.x; i < NBINS; i += 256)
    if (hh[i]) atomicAdd(&ghist[i], hh[i]);
}

// ---------------- K9: screening threshold, SLACK_BINS below the k-th bin ----------------
__global__ __launch_bounds__(1024) void thresh_k(const unsigned* __restrict__ hist,
                                                 float* __restrict__ T_lo) {
  __shared__ unsigned suff[1024];
  int t = threadIdx.x;
  const int G = NBINS / 1024;
  int b0 = t * G;
  unsigned s = 0;
  for (int j = 0; j < G; ++j) s += hist[b0 + j];
  unsigned v = s;
  suff[t] = v; __syncthreads();
  for (int o = 1; o < 1024; o <<= 1) {
    unsigned add = (t + o < 1024) ? suff[t + o] : 0u;
    __syncthreads();
    v += add; suff[t] = v;
    __syncthreads();
  }
  unsigned above = (t < 1023) ? suff[t + 1] : 0u;
  if (above < (unsigned)K_TOP && suff[t] >= (unsigned)K_TOP) {
    unsigned running = above;
    int B = b0;
    for (int b = b0 + G - 1; b >= b0; --b) {
      running += hist[b];
      if (running >= (unsigned)K_TOP) { B = b; break; }
    }
    B = max(B, SLACK_BINS);
    *T_lo = (float)(B - SLACK_BINS) * (1.0f / 4096.0f) - 1.0f;
  }
}

// ---------------- K10: compact candidate positions >= T_lo ----------------
__global__ void collect_k(const float4* __restrict__ S4, const float* __restrict__ T_lo_p,
                          unsigned* __restrict__ counter, int* __restrict__ ci) {
  float T = *T_lo_p;
  int stride = gridDim.x * blockDim.x;
  for (int i = blockIdx.x * blockDim.x + threadIdx.x; i < S_TOTAL / 4; i += stride) {
    float4 v = S4[i];
    float vv[4] = {v.x, v.y, v.z, v.w};
#pragma unroll
    for (int c = 0; c < 4; ++c) {
      if (vv[c] >= T) {
        unsigned j = atomicAdd(counter, 1u);
        if (j < CAP2) ci[j] = i * 4 + c;
      }
    }
  }
}

// ---------------- K11: FULL f64 rescore -> monotone u64 key (1 wave / candidate) ----------------
__global__ __launch_bounds__(256) void rescore_k(const float* __restrict__ X,
                                                 const float* __restrict__ W,
                                                 const int* __restrict__ V,
                                                 const int* __restrict__ cnt,
                                                 const int* __restrict__ offs,
                                                 const int* __restrict__ bucket,
                                                 const int* __restrict__ ci,
                                                 const unsigned* __restrict__ counter,
                                                 unsigned long long* __restrict__ ckey) {
  int C = (int)min(*counter, (unsigned)CAP2);
  int wave = threadIdx.x >> 6, lane = threadIdx.x & 63;
  int j = blockIdx.x * 4 + wave;
  if (j >= C) return;
  int pos = ci[j];
  int n = pos >> 13;
  int m = pos & 8191;
  int deg = cnt[m], off = offs[m];
  int nmem = min(deg, 512);
  double e0 = 0.0, e1 = 0.0;
  for (int q = 0; q < nmem; ++q) {
    const float* xv = X + (size_t)V[bucket[off + q]] * EMB;
    e0 += (double)xv[lane];
    e1 += (double)xv[lane + 64];
  }
  double dd = fmax((double)deg, 1.0);
  e0 /= dd; e1 /= dd;
  const float* xr = X + (size_t)n * EMB;
  double x0 = (double)xr[lane], x1 = (double)xr[lane + 64];
  double s = 0.0;
  for (int h = 0; h < NHEAD; ++h) {
    const float* wr = W + h * EMB;
    double w0 = (double)wr[lane], w1 = (double)wr[lane + 64];
    double xw0 = x0 * w0, xw1 = x1 * w1;
    double ew0 = e0 * w0, ew1 = e1 * w1;
    double an = xw0 * xw0 + xw1 * xw1;
    double ae = ew0 * ew0 + ew1 * ew1;
    double dt = xw0 * ew0 + xw1 * ew1;
    for (int o = 32; o > 0; o >>= 1) {
      an += __shfl_down(an, o, 64);
      ae += __shfl_down(ae, o, 64);
      dt += __shfl_down(dt, o, 64);
    }
    if (lane == 0) {
      double Nn = fmax(sqrt(an), 1e-6);
      double Ne = fmax(sqrt(ae), 1e-6);
      s += dt / (Nn * Ne);
    }
  }
  if (lane == 0) ckey[j] = f64key(s * 0.25);
}

// ---------------- K12: exact k-th largest key via 8-level byte radix select ----------------
__global__ __launch_bounds__(1024) void kth_k(const unsigned long long* __restrict__ keys,
                                              const unsigned* __restrict__ counter,
                                              unsigned long long* __restrict__ thr) {
  __shared__ unsigned hist[256];
  __shared__ unsigned long long s_prefix;
  __shared__ unsigned s_kleft, s_cgreat;
  int C = (int)min(*counter, (unsigned)CAP2);
  if (threadIdx.x == 0) { s_prefix = 0ULL; s_kleft = K_TOP; s_cgreat = 0u; }
  __syncthreads();
  for (int level = 7; level >= 0; --level) {
    for (int i = threadIdx.x; i < 256; i += 1024) hist[i] = 0;
    __syncthreads();
    unsigned long long prefix = s_prefix;
    unsigned long long pmask = (level == 7) ? 0ULL : (~0ULL << ((level + 1) * 8));
    for (int i = threadIdx.x; i < C; i += 1024) {
      unsigned long long k = keys[i];
      if ((k & pmask) == prefix)
        atomicAdd(&hist[(unsigned)((k >> (level * 8)) & 0xFF)], 1u);
    }
    __syncthreads();
    if (threadIdx.x == 0) {
      unsigned cum = 0; int b = 0;
      for (int i = 255; i >= 0; --i) {
        if (cum + hist[i] >= s_kleft) { b = i; break; }
        cum += hist[i];
      }
      s_prefix |= ((unsigned long long)b << (level * 8));
      s_kleft  -= cum;
      s_cgreat += cum;
    }
    __syncthreads();
  }
  if (threadIdx.x == 0) { thr[0] = s_prefix; thr[1] = (unsigned long long)s_cgreat; }
}

// ---------------- K13: write masks for key > thr; gather ties at key == thr ----------------
__global__ void write_k(const unsigned long long* __restrict__ keys,
                        const int* __restrict__ ci,
                        const unsigned* __restrict__ counter,
                        const unsigned long long* __restrict__ thr,
                        const float* __restrict__ P, float* __restrict__ out,
                        int* __restrict__ tiebuf, unsigned* __restrict__ tiecnt) {
  int C = (int)min(*counter, (unsigned)CAP2);
  int j = blockIdx.x * blockDim.x + threadIdx.x;
  if (j >= C) return;
  unsigned long long k = keys[j];
  unsigned long long t = thr[0];
  if (k > t) {
    unsigned pos = (unsigned)ci[j];
    out[pos] = mask_val(P[pos], pos);
  } else if (k == t) {
    unsigned q = atomicAdd(tiecnt, 1u);
    if (q < TIE_CAP) tiebuf[q] = ci[j];
  }
}

// ---------------- K14: fill remaining slots from ties, ascending index ----------------
__global__ __launch_bounds__(256) void tiefin_k(const int* __restrict__ tiebuf,
                                                const unsigned* __restrict__ tiecnt,
                                                const unsigned long long* __restrict__ thr,
                                                const float* __restrict__ P,
                                                float* __restrict__ out) {
  __shared__ int idx[TIE_CAP];
  int T = (int)min(*tiecnt, (unsigned)TIE_CAP);
  int need = K_TOP - (int)thr[1];
  if (need <= 0 || T == 0) return;       // uniform exit
  for (int i = threadIdx.x; i < T; i += 256) idx[i] = tiebuf[i];
  __syncthreads();
  if (threadIdx.x == 0 && T > 1) {       // ascending flat index (top_k stable order)
    for (int a = 1; a < T; ++a) {
      int key = idx[a]; int b = a - 1;
      while (b >= 0 && idx[b] > key) { idx[b + 1] = idx[b]; --b; }
      idx[b + 1] = key;
    }
  }
  __syncthreads();
  int m = min(need, T);
  for (int i = threadIdx.x; i < m; i += 256) {
    unsigned pos = (unsigned)idx[i];
    out[pos] = mask_val(P[pos], pos);
  }
}

// ---------------- K15: H positions (the (V,E) pairs) ----------------
__global__ void scatterH_k(const int* __restrict__ V, const int* __restrict__ E,
                           const float* __restrict__ P, float* __restrict__ out) {
  int i = blockIdx.x * blockDim.x + threadIdx.x;
  if (i >= NNZ) return;
  unsigned pos = (unsigned)V[i] * (unsigned)N_EDGES + (unsigned)E[i];
  out[pos] = mask_val(P[pos], pos);
}

extern "C" void kernel_launch(void* const* d_in, const int* in_sizes, int n_in,
                              void* d_out, int out_size, void* d_ws, size_t ws_size,
                              hipStream_t stream) {
  const float* X = (const float*)d_in[0];
  // d_in[1] = H (unused: nonzeros are exactly the (V,E) pairs)
  const int*   V = (const int*)d_in[2];
  const int*   E = (const int*)d_in[3];
  const float* P = (const float*)d_in[4];
  const float* W = (const float*)d_in[5];
  float* S = (float*)d_out;                 // out buffer doubles as the score matrix

  // ws layout — ~6.1 MB. R7 BUG WAS HERE: eX at 2166784 overlapped ne's last 256 B.
  char* w = (char*)d_ws;
  int*      cnt      = (int*)(w + 0);            // 32 KB
  int*      offs     = (int*)(w + 32768);        // 32 KB
  int*      cursor   = (int*)(w + 65536);        // 32 KB
  int*      bucket   = (int*)(w + 98304);        // 256 KB -> 360448
  unsigned* hist     = (unsigned*)(w + 360448);  // 32 KB  -> 393216
  unsigned* counter  = (unsigned*)(w + 393216);  // 4 B
  float*    T_lo     = (float*)(w + 393220);     // 4 B
  unsigned* tiecnt   = (unsigned*)(w + 393224);  // 4 B
  unsigned long long* thr = (unsigned long long*)(w + 393232); // 16 B
  int*      cand_idx = (int*)(w + 393472);       // 512 KB -> 917760
  unsigned long long* cand_key = (unsigned long long*)(w + 917760); // 1 MB -> 1966336
  int*      tiebuf   = (int*)(w + 1966336);      // 4 KB   -> 1970432
  float*    nn       = (float*)(w + 1970432);    // 64 KB  -> 2035968
  float*    ne       = (float*)(w + 2035968);    // 128 KB -> 2167040
  float*    eX       = (float*)(w + 2167040);    // 4 MB   -> 6361344  (FIXED)

  hipMemsetAsync(cnt,     0, 32768, stream);
  hipMemsetAsync(cursor,  0, 32768, stream);
  hipMemsetAsync(hist,    0, NBINS * 4, stream);
  hipMemsetAsync(counter, 0, 48, stream);        // zeroes counter, T_lo, tiecnt, thr

  count_k   <<<NNZ / 256, 256, 0, stream>>>(E, cnt);
  scan_k    <<<1, 1024, 0, stream>>>(cnt, offs);
  scatter_k <<<NNZ / 256, 256, 0, stream>>>(E, offs, cursor, bucket);
  edge_k    <<<N_EDGES, 128, 0, stream>>>(X, V, cnt, offs, bucket, W, eX, ne);
  node_k    <<<N_CODES, 128, 0, stream>>>(X, W, nn);
  gemm_fused<<<dim3(N_EDGES / 128, N_CODES / 128), 256, 0, stream>>>(X, eX, W, nn, ne, S);
  maskset_k <<<NNZ / 256, 256, 0, stream>>>(V, E, S);
  hist_k    <<<512, 256, 0, stream>>>((const float4*)S, hist);
  thresh_k  <<<1, 1024, 0, stream>>>(hist, T_lo);
  collect_k <<<1024, 256, 0, stream>>>((const float4*)S, T_lo, counter, cand_idx);
  rescore_k <<<CAP2 / 4, 256, 0, stream>>>(X, W, V, cnt, offs, bucket,
                                           cand_idx, counter, cand_key);
  kth_k     <<<1, 1024, 0, stream>>>(cand_key, counter, thr);
  hipMemsetAsync(d_out, 0, (size_t)S_TOTAL * 4, stream);
  write_k   <<<CAP2 / 256, 256, 0, stream>>>(cand_key, cand_idx, counter, thr,
                                             P, S, tiebuf, tiecnt);
  tiefin_k  <<<1, 256, 0, stream>>>(tiebuf, tiecnt, thr, P, S);
  scatterH_k<<<NNZ / 256, 256, 0, stream>>>(V, E, P, S);
}